// Round 1
// baseline (2281.350 us; speedup 1.0000x reference)
//
#include <hip/hip_runtime.h>
#include <math.h>

constexpr int Bb = 4;      // batch
constexpr int Nn = 2048;   // tokens per batch
constexpr int Dd = 2048;   // model dim (K)
constexpr int Ee = 8;      // experts
constexpr int Cbn = 512;   // bottleneck dim
constexpr int Mm = Bb * Nn; // 8192 total tokens

// ---------------- GEMM + fused square-reduce --------------------------------
// logits2[t,e] = sum_c ( x_t . W_e[:,c] )^2
// grid: (Mm/64, Ee); block 256 threads. Tile: 64 tokens x 128 c-cols, BK=32.
__global__ __launch_bounds__(256) void gemm_sq(const float* __restrict__ X,
                                               const float* __restrict__ W,
                                               float* __restrict__ logits2) {
  constexpr int BM = 64, BN = 128, BK = 32;
  const int mtile = blockIdx.x;
  const int e = blockIdx.y;
  const int tid = threadIdx.x;
  const float* Xb = X + (size_t)mtile * BM * Dd;
  const float* Wb = W + (size_t)e * Dd * Cbn;

  __shared__ float As[BK][BM + 1];  // transposed A tile, +1 pad
  __shared__ float Bs[BK][BN];

  const int ty = tid >> 4;  // 0..15 -> token rows ty*4..ty*4+3
  const int tx = tid & 15;  // 0..15 -> c cols tx*8..tx*8+7

  float sumsq[4] = {0.f, 0.f, 0.f, 0.f};

  for (int ct = 0; ct < Cbn; ct += BN) {
    float acc[4][8];
#pragma unroll
    for (int i = 0; i < 4; ++i)
#pragma unroll
      for (int j = 0; j < 8; ++j) acc[i][j] = 0.f;

    for (int k0 = 0; k0 < Dd; k0 += BK) {
      // A tile: 64 rows x 32 k (512 float4, 2 per thread)
#pragma unroll
      for (int i = 0; i < 2; ++i) {
        int f = tid + i * 256;
        int row = f >> 3, c4 = (f & 7) << 2;
        float4 v = *(const float4*)(Xb + (size_t)row * Dd + k0 + c4);
        As[c4 + 0][row] = v.x;
        As[c4 + 1][row] = v.y;
        As[c4 + 2][row] = v.z;
        As[c4 + 3][row] = v.w;
      }
      // W tile: 32 k-rows x 128 c (1024 float4, 4 per thread)
#pragma unroll
      for (int i = 0; i < 4; ++i) {
        int f = tid + i * 256;
        int row = f >> 5, c4 = (f & 31) << 2;
        *(float4*)(&Bs[row][c4]) =
            *(const float4*)(Wb + (size_t)(k0 + row) * Cbn + ct + c4);
      }
      __syncthreads();
#pragma unroll
      for (int kk = 0; kk < BK; ++kk) {
        float aa[4];
        aa[0] = As[kk][ty * 4 + 0];
        aa[1] = As[kk][ty * 4 + 1];
        aa[2] = As[kk][ty * 4 + 2];
        aa[3] = As[kk][ty * 4 + 3];
        float4 b0 = *(const float4*)(&Bs[kk][tx * 8]);
        float4 b1 = *(const float4*)(&Bs[kk][tx * 8 + 4]);
        float bj[8] = {b0.x, b0.y, b0.z, b0.w, b1.x, b1.y, b1.z, b1.w};
#pragma unroll
        for (int i = 0; i < 4; ++i)
#pragma unroll
          for (int j = 0; j < 8; ++j) acc[i][j] = fmaf(aa[i], bj[j], acc[i][j]);
      }
      __syncthreads();
    }
#pragma unroll
    for (int i = 0; i < 4; ++i)
#pragma unroll
      for (int j = 0; j < 8; ++j) sumsq[i] += acc[i][j] * acc[i][j];
  }

  // reduce partial sums over the 16 tx groups
  __shared__ float red[16][17];
#pragma unroll
  for (int i = 0; i < 4; ++i) {
    red[ty][tx] = sumsq[i];
    __syncthreads();
    if (tx == 0) {
      float s = 0.f;
#pragma unroll
      for (int u = 0; u < 16; ++u) s += red[ty][u];
      logits2[(size_t)(mtile * BM + ty * 4 + i) * Ee + e] = s;
    }
    __syncthreads();
  }
}

// ---------------- softmax + top-2 per token ---------------------------------
__global__ void route_kernel(const float* __restrict__ logits2,
                             int* __restrict__ idx1, int* __restrict__ idx2,
                             float* __restrict__ p1, float* __restrict__ p2) {
  int t = blockIdx.x * blockDim.x + threadIdx.x;
  if (t >= Mm) return;
  float l[Ee];
  float mx = -1e30f;
#pragma unroll
  for (int e = 0; e < Ee; ++e) {
    l[e] = sqrtf(logits2[(size_t)t * Ee + e]);
    mx = fmaxf(mx, l[e]);
  }
  float p[Ee];
  float s = 0.f;
#pragma unroll
  for (int e = 0; e < Ee; ++e) {
    p[e] = expf(l[e] - mx);
    s += p[e];
  }
  float inv = 1.f / s;
  // top-1 (strict > keeps lowest index on ties, matching lax.top_k)
  int i1 = 0;
  float b1 = l[0];
#pragma unroll
  for (int e = 1; e < Ee; ++e)
    if (l[e] > b1) { b1 = l[e]; i1 = e; }
  int i2 = -1;
  float b2 = -1e30f;
#pragma unroll
  for (int e = 0; e < Ee; ++e)
    if (e != i1 && l[e] > b2) { b2 = l[e]; i2 = e; }
  idx1[t] = i1;
  idx2[t] = i2;
  p1[t] = p[i1] * inv;
  p2[t] = p[i2] * inv;
}

// ---------------- per-batch capacity priority scan --------------------------
// Order per batch: positions p = k*N + n (all top-1 slots, then all top-2).
// prio[p] = number of earlier positions choosing the same expert.
__global__ void scan_kernel(const int* __restrict__ idx1,
                            const int* __restrict__ idx2,
                            int* __restrict__ prios) {
  const int b = blockIdx.x;
  const int tid = threadIdx.x;  // 256 threads x 16 positions = 4096
  __shared__ int cnts[256][8];

  int cnt[8] = {0, 0, 0, 0, 0, 0, 0, 0};
  int eloc[16];
  const int base_p = tid * 16;
#pragma unroll
  for (int i = 0; i < 16; ++i) {
    int p = base_p + i;
    int k = p >> 11;          // 0 or 1
    int n = p & (Nn - 1);
    int e = (k == 0 ? idx1 : idx2)[b * Nn + n];
    eloc[i] = e;
    cnt[e]++;
  }
#pragma unroll
  for (int e = 0; e < 8; ++e) cnts[tid][e] = cnt[e];
  __syncthreads();
  if (tid < 8) {  // serial exclusive prefix per expert (256 adds, tiny)
    int run = 0;
    for (int i = 0; i < 256; ++i) {
      int v = cnts[i][tid];
      cnts[i][tid] = run;
      run += v;
    }
  }
  __syncthreads();
  int base[8];
#pragma unroll
  for (int e = 0; e < 8; ++e) base[e] = cnts[tid][e];
#pragma unroll
  for (int i = 0; i < 16; ++i) {
    int e = eloc[i];
    prios[b * 2 * Nn + base_p + i] = base[e]++;
  }
}

// ---------------- zero the output -------------------------------------------
__global__ void zero_kernel(float4* __restrict__ out, int n4) {
  int i = blockIdx.x * blockDim.x + threadIdx.x;
  if (i < n4) out[i] = make_float4(0.f, 0.f, 0.f, 0.f);
}

// ---------------- scatter dispatch/combine ----------------------------------
__global__ void scatter_kernel(const int* __restrict__ idx1,
                               const int* __restrict__ idx2,
                               const float* __restrict__ p1,
                               const float* __restrict__ p2,
                               const int* __restrict__ prios,
                               float* __restrict__ out, int cap) {
  int t = blockIdx.x * blockDim.x + threadIdx.x;
  if (t >= Mm) return;
  int b = t >> 11;
  int n = t & (Nn - 1);
  size_t disp = (size_t)t * Ee * cap;            // (((0*B+b)*N+n)*E)*cap
  size_t comb = disp + (size_t)Mm * Ee * cap;    // + B*N*E*cap
  {
    int e = idx1[t];
    int p = prios[b * 2 * Nn + n];
    if (p < cap) {
      out[disp + (size_t)e * cap + p] = 1.f;
      out[comb + (size_t)e * cap + p] = p1[t];
    }
  }
  {
    int e = idx2[t];
    int p = prios[b * 2 * Nn + Nn + n];
    if (p < cap) {
      out[disp + (size_t)e * cap + p] = 1.f;
      out[comb + (size_t)e * cap + p] = p2[t];
    }
  }
}

extern "C" void kernel_launch(void* const* d_in, const int* in_sizes, int n_in,
                              void* d_out, int out_size, void* d_ws, size_t ws_size,
                              hipStream_t stream) {
  const float* X = (const float*)d_in[0];  // [B,N,D]
  const float* W = (const float*)d_in[1];  // [E,D,Cbn]
  float* out = (float*)d_out;              // [2,B,N,E,cap]
  const int cap = out_size / (2 * Bb * Nn * Ee);  // 640

  char* ws = (char*)d_ws;
  float* logits2 = (float*)ws;                      // Mm*Ee f32   (256 KB)
  int* idx1 = (int*)(ws + (size_t)512 * 1024);
  int* idx2 = idx1 + Mm;
  float* p1 = (float*)(idx2 + Mm);
  float* p2 = p1 + Mm;
  int* prios = (int*)(p2 + Mm);                     // Bb*2*Nn int

  gemm_sq<<<dim3(Mm / 64, Ee), 256, 0, stream>>>(X, W, logits2);
  route_kernel<<<Mm / 256, 256, 0, stream>>>(logits2, idx1, idx2, p1, p2);
  scan_kernel<<<Bb, 256, 0, stream>>>(idx1, idx2, prios);
  const int n4 = out_size / 4;
  zero_kernel<<<(n4 + 255) / 256, 256, 0, stream>>>((float4*)out, n4);
  scatter_kernel<<<Mm / 256, 256, 0, stream>>>(idx1, idx2, p1, p2, prios, out, cap);
}

// Round 2
// 820.132 us; speedup vs baseline: 2.7817x; 2.7817x over previous
//
#include <hip/hip_runtime.h>
#include <math.h>

constexpr int Bb = 4, Nn = 2048, Dd = 2048, Ee = 8, Cbn = 512;
constexpr int Mm = Bb * Nn;          // 8192 tokens
constexpr int Ncols = Ee * Cbn;      // 4096 concatenated bottleneck cols

typedef _Float16 half8 __attribute__((ext_vector_type(8)));
typedef _Float16 half4v __attribute__((ext_vector_type(4)));
typedef float floatx16 __attribute__((ext_vector_type(16)));

#define GLL16(g, l)                                                     \
  __builtin_amdgcn_global_load_lds(                                     \
      (const __attribute__((address_space(1))) void*)(g),               \
      (__attribute__((address_space(3))) void*)(l), 16, 0, 0)

// ---------------- split X fp32 -> fp16 hi + lo ------------------------------
__global__ __launch_bounds__(256) void split_x(const float* __restrict__ X,
                                               _Float16* __restrict__ hi,
                                               _Float16* __restrict__ lo) {
  int i = (blockIdx.x * 256 + threadIdx.x) * 4;
  float4 v = *(const float4*)(X + i);
  half4v h, l;
  h.x = (_Float16)v.x; l.x = (_Float16)(v.x - (float)h.x);
  h.y = (_Float16)v.y; l.y = (_Float16)(v.y - (float)h.y);
  h.z = (_Float16)v.z; l.z = (_Float16)(v.z - (float)h.z);
  h.w = (_Float16)v.w; l.w = (_Float16)(v.w - (float)h.w);
  *(half4v*)(hi + i) = h;
  *(half4v*)(lo + i) = l;
}

// ---------------- transpose + split W: [E,D,C] f32 -> WT[hi/lo][E*C][D] -----
__global__ __launch_bounds__(256) void transpose_w(const float* __restrict__ W,
                                                   _Float16* __restrict__ WThi,
                                                   _Float16* __restrict__ WTlo) {
  const int kt = blockIdx.x;  // 0..31 (k tiles of 64)
  const int ct = blockIdx.y;  // 0..7  (c tiles of 64)
  const int e = blockIdx.z;   // 0..7
  __shared__ _Float16 thi[64][68];
  __shared__ _Float16 tlo[64][68];
  const int tx = threadIdx.x & 15, ty = threadIdx.x >> 4;
  const float* src = W + ((size_t)(e * 2048 + kt * 64)) * 512 + ct * 64;
#pragma unroll
  for (int p = 0; p < 4; ++p) {
    int kk = ty + p * 16;
    float4 v = *(const float4*)(src + (size_t)kk * 512 + tx * 4);
    _Float16 h;
    h = (_Float16)v.x; thi[tx * 4 + 0][kk] = h; tlo[tx * 4 + 0][kk] = (_Float16)(v.x - (float)h);
    h = (_Float16)v.y; thi[tx * 4 + 1][kk] = h; tlo[tx * 4 + 1][kk] = (_Float16)(v.y - (float)h);
    h = (_Float16)v.z; thi[tx * 4 + 2][kk] = h; tlo[tx * 4 + 2][kk] = (_Float16)(v.z - (float)h);
    h = (_Float16)v.w; thi[tx * 4 + 3][kk] = h; tlo[tx * 4 + 3][kk] = (_Float16)(v.w - (float)h);
  }
  __syncthreads();
  _Float16* dh = WThi + ((size_t)(e * 512 + ct * 64)) * 2048 + kt * 64;
  _Float16* dl = WTlo + ((size_t)(e * 512 + ct * 64)) * 2048 + kt * 64;
#pragma unroll
  for (int p = 0; p < 4; ++p) {
    int cc = ty + p * 16;
    half4v h, l;
    h.x = thi[cc][tx * 4 + 0]; l.x = tlo[cc][tx * 4 + 0];
    h.y = thi[cc][tx * 4 + 1]; l.y = tlo[cc][tx * 4 + 1];
    h.z = thi[cc][tx * 4 + 2]; l.z = tlo[cc][tx * 4 + 2];
    h.w = thi[cc][tx * 4 + 3]; l.w = tlo[cc][tx * 4 + 3];
    *(half4v*)(dh + (size_t)cc * 2048 + tx * 4) = h;
    *(half4v*)(dl + (size_t)cc * 2048 + tx * 4) = l;
  }
}

// ---------------- MFMA GEMM + fused square-reduce ---------------------------
// C = X(8192x2048) * WT^T(2048x4096); partial[slice][t] = sum_{64 cols} C^2
// block: 128x128 tile, 4 waves of 64x64, 32x32x16 f16 MFMA, split-fp16 x3.
__global__ __launch_bounds__(256) void gemm_mfma(const _Float16* __restrict__ Xhi,
                                                 const _Float16* __restrict__ Xlo,
                                                 const _Float16* __restrict__ WThi,
                                                 const _Float16* __restrict__ WTlo,
                                                 float* __restrict__ partial) {
  const int mtile = blockIdx.x;  // 64
  const int ntile = blockIdx.y;  // 32
  const int tid = threadIdx.x;
  const int wave = tid >> 6, lane = tid & 63;
  const int wm = wave >> 1, wn = wave & 1;
  const int h = lane >> 5;

  __shared__ __align__(16) char lds[32768];
  char* ldsAhi = lds;
  char* ldsAlo = lds + 8192;
  char* ldsBhi = lds + 16384;
  char* ldsBlo = lds + 24576;

  // ---- staging addressing: tile row r holds its 4 16B chunks XOR-swizzled
  // by ((r>>1)&3); DMA writes LDS base + lane*16, so lane fetches the global
  // chunk that belongs at its position.
  const int lr = lane >> 2;       // row within 16-row chunk
  const int cpos = lane & 3;      // chunk position in LDS
  const int cg = cpos ^ ((lr >> 1) & 3);  // global 16B chunk to fetch
  const int r0 = wave * 32 + lr;
  const int r1 = r0 + 16;
  const _Float16* xh0 = Xhi + (size_t)(mtile * 128 + r0) * 2048 + cg * 8;
  const _Float16* xh1 = Xhi + (size_t)(mtile * 128 + r1) * 2048 + cg * 8;
  const _Float16* xl0 = Xlo + (size_t)(mtile * 128 + r0) * 2048 + cg * 8;
  const _Float16* xl1 = Xlo + (size_t)(mtile * 128 + r1) * 2048 + cg * 8;
  const _Float16* wh0 = WThi + (size_t)(ntile * 128 + r0) * 2048 + cg * 8;
  const _Float16* wh1 = WThi + (size_t)(ntile * 128 + r1) * 2048 + cg * 8;
  const _Float16* wl0 = WTlo + (size_t)(ntile * 128 + r0) * 2048 + cg * 8;
  const _Float16* wl1 = WTlo + (size_t)(ntile * 128 + r1) * 2048 + cg * 8;
  const int lq0 = wave * 2048;  // LDS byte base of this wave's chunk 2w
  const int lq1 = lq0 + 1024;

  // ---- fragment read offsets (bytes within a tile)
  const int rA0 = wm * 64 + (lane & 31);
  const int rA1 = rA0 + 32;
  const int rB0 = wn * 64 + (lane & 31);
  const int rB1 = rB0 + 32;
  auto foff = [&](int r, int s) {
    return r * 64 + (((s * 2 + h) ^ ((r >> 1) & 3)) << 4);
  };
  const int oA0[2] = {foff(rA0, 0), foff(rA0, 1)};
  const int oA1[2] = {foff(rA1, 0), foff(rA1, 1)};
  const int oB0[2] = {foff(rB0, 0), foff(rB0, 1)};
  const int oB1[2] = {foff(rB1, 0), foff(rB1, 1)};

  floatx16 acc00 = {}, acc01 = {}, acc10 = {}, acc11 = {};

  for (int kt = 0; kt < 64; ++kt) {
    const int k0 = kt * 32;
    GLL16(xh0 + k0, ldsAhi + lq0);
    GLL16(xh1 + k0, ldsAhi + lq1);
    GLL16(xl0 + k0, ldsAlo + lq0);
    GLL16(xl1 + k0, ldsAlo + lq1);
    GLL16(wh0 + k0, ldsBhi + lq0);
    GLL16(wh1 + k0, ldsBhi + lq1);
    GLL16(wl0 + k0, ldsBlo + lq0);
    GLL16(wl1 + k0, ldsBlo + lq1);
    __syncthreads();  // drains vmcnt -> LDS tiles valid
#pragma unroll
    for (int s = 0; s < 2; ++s) {
      half8 ah0 = *(const half8*)(ldsAhi + oA0[s]);
      half8 ah1 = *(const half8*)(ldsAhi + oA1[s]);
      half8 al0 = *(const half8*)(ldsAlo + oA0[s]);
      half8 al1 = *(const half8*)(ldsAlo + oA1[s]);
      half8 bh0 = *(const half8*)(ldsBhi + oB0[s]);
      half8 bh1 = *(const half8*)(ldsBhi + oB1[s]);
      half8 bl0 = *(const half8*)(ldsBlo + oB0[s]);
      half8 bl1 = *(const half8*)(ldsBlo + oB1[s]);
      acc00 = __builtin_amdgcn_mfma_f32_32x32x16_f16(ah0, bh0, acc00, 0, 0, 0);
      acc00 = __builtin_amdgcn_mfma_f32_32x32x16_f16(ah0, bl0, acc00, 0, 0, 0);
      acc00 = __builtin_amdgcn_mfma_f32_32x32x16_f16(al0, bh0, acc00, 0, 0, 0);
      acc01 = __builtin_amdgcn_mfma_f32_32x32x16_f16(ah0, bh1, acc01, 0, 0, 0);
      acc01 = __builtin_amdgcn_mfma_f32_32x32x16_f16(ah0, bl1, acc01, 0, 0, 0);
      acc01 = __builtin_amdgcn_mfma_f32_32x32x16_f16(al0, bh1, acc01, 0, 0, 0);
      acc10 = __builtin_amdgcn_mfma_f32_32x32x16_f16(ah1, bh0, acc10, 0, 0, 0);
      acc10 = __builtin_amdgcn_mfma_f32_32x32x16_f16(ah1, bl0, acc10, 0, 0, 0);
      acc10 = __builtin_amdgcn_mfma_f32_32x32x16_f16(al1, bh0, acc10, 0, 0, 0);
      acc11 = __builtin_amdgcn_mfma_f32_32x32x16_f16(ah1, bh1, acc11, 0, 0, 0);
      acc11 = __builtin_amdgcn_mfma_f32_32x32x16_f16(ah1, bl1, acc11, 0, 0, 0);
      acc11 = __builtin_amdgcn_mfma_f32_32x32x16_f16(al1, bh1, acc11, 0, 0, 0);
    }
    __syncthreads();
  }

  // ---- epilogue: per-row sum of squares over this wave's 64 cols
  // C/D layout 32x32: col=lane&31, row=(reg&3)+8*(reg>>2)+4*(lane>>5)
  float myv = 0.f;
#pragma unroll
  for (int i = 0; i < 2; ++i) {
    const floatx16& c0 = i ? acc10 : acc00;
    const floatx16& c1 = i ? acc11 : acc01;
#pragma unroll
    for (int reg = 0; reg < 16; ++reg) {
      float v = c0[reg] * c0[reg] + c1[reg] * c1[reg];
#pragma unroll
      for (int m = 1; m <= 16; m <<= 1) v += __shfl_xor(v, m, 64);
      if ((lane & 31) == i * 16 + reg) myv = v;
    }
  }
  {
    const int i = (lane & 31) >> 4;
    const int reg = lane & 15;
    const int row = i * 32 + (reg & 3) + 8 * (reg >> 2) + 4 * h;
    const int token = mtile * 128 + wm * 64 + row;
    const int slice = ntile * 2 + wn;  // = (e*4+cb)*2+wn = e*8+u
    partial[(size_t)slice * Mm + token] = myv;
  }
}

// ---------------- softmax + top-2 per token ---------------------------------
__global__ void route_kernel(const float* __restrict__ partial,
                             int* __restrict__ idx1, int* __restrict__ idx2,
                             float* __restrict__ p1, float* __restrict__ p2) {
  int t = blockIdx.x * blockDim.x + threadIdx.x;
  if (t >= Mm) return;
  float l[Ee];
  float mx = -1e30f;
#pragma unroll
  for (int e = 0; e < Ee; ++e) {
    float s = 0.f;
#pragma unroll
    for (int u = 0; u < 8; ++u) s += partial[(size_t)(e * 8 + u) * Mm + t];
    l[e] = sqrtf(s);
    mx = fmaxf(mx, l[e]);
  }
  float p[Ee];
  float s = 0.f;
#pragma unroll
  for (int e = 0; e < Ee; ++e) {
    p[e] = expf(l[e] - mx);
    s += p[e];
  }
  float inv = 1.f / s;
  int i1 = 0;
  float b1 = l[0];
#pragma unroll
  for (int e = 1; e < Ee; ++e)
    if (l[e] > b1) { b1 = l[e]; i1 = e; }
  int i2 = -1;
  float b2 = -1e30f;
#pragma unroll
  for (int e = 0; e < Ee; ++e)
    if (e != i1 && l[e] > b2) { b2 = l[e]; i2 = e; }
  idx1[t] = i1;
  idx2[t] = i2;
  p1[t] = p[i1] * inv;
  p2[t] = p[i2] * inv;
}

// ---------------- per-batch capacity priority scan --------------------------
__global__ void scan_kernel(const int* __restrict__ idx1,
                            const int* __restrict__ idx2,
                            int* __restrict__ prios) {
  const int b = blockIdx.x;
  const int tid = threadIdx.x;
  __shared__ int cnts[256][8];
  int cnt[8] = {0, 0, 0, 0, 0, 0, 0, 0};
  int eloc[16];
  const int base_p = tid * 16;
#pragma unroll
  for (int i = 0; i < 16; ++i) {
    int p = base_p + i;
    int k = p >> 11;
    int n = p & (Nn - 1);
    int e = (k == 0 ? idx1 : idx2)[b * Nn + n];
    eloc[i] = e;
    cnt[e]++;
  }
#pragma unroll
  for (int e = 0; e < 8; ++e) cnts[tid][e] = cnt[e];
  __syncthreads();
  if (tid < 8) {
    int run = 0;
    for (int i = 0; i < 256; ++i) {
      int v = cnts[i][tid];
      cnts[i][tid] = run;
      run += v;
    }
  }
  __syncthreads();
  int base[8];
#pragma unroll
  for (int e = 0; e < 8; ++e) base[e] = cnts[tid][e];
#pragma unroll
  for (int i = 0; i < 16; ++i) {
    int e = eloc[i];
    prios[b * 2 * Nn + base_p + i] = base[e]++;
  }
}

// ---------------- zero output ------------------------------------------------
__global__ void zero_kernel(float4* __restrict__ out, int n4) {
  int i = blockIdx.x * blockDim.x + threadIdx.x;
  if (i < n4) out[i] = make_float4(0.f, 0.f, 0.f, 0.f);
}

// ---------------- scatter dispatch/combine ----------------------------------
__global__ void scatter_kernel(const int* __restrict__ idx1,
                               const int* __restrict__ idx2,
                               const float* __restrict__ p1,
                               const float* __restrict__ p2,
                               const int* __restrict__ prios,
                               float* __restrict__ out, int cap) {
  int t = blockIdx.x * blockDim.x + threadIdx.x;
  if (t >= Mm) return;
  int b = t >> 11;
  int n = t & (Nn - 1);
  size_t disp = (size_t)t * Ee * cap;
  size_t comb = disp + (size_t)Mm * Ee * cap;
  {
    int e = idx1[t];
    int p = prios[b * 2 * Nn + n];
    if (p < cap) {
      out[disp + (size_t)e * cap + p] = 1.f;
      out[comb + (size_t)e * cap + p] = p1[t];
    }
  }
  {
    int e = idx2[t];
    int p = prios[b * 2 * Nn + Nn + n];
    if (p < cap) {
      out[disp + (size_t)e * cap + p] = 1.f;
      out[comb + (size_t)e * cap + p] = p2[t];
    }
  }
}

extern "C" void kernel_launch(void* const* d_in, const int* in_sizes, int n_in,
                              void* d_out, int out_size, void* d_ws, size_t ws_size,
                              hipStream_t stream) {
  const float* X = (const float*)d_in[0];
  const float* W = (const float*)d_in[1];
  float* out = (float*)d_out;
  const int cap = out_size / (2 * Bb * Nn * Ee);  // 640

  char* ws = (char*)d_ws;
  _Float16* Xhi = (_Float16*)ws;                       // 33,554,432 B
  _Float16* Xlo = (_Float16*)(ws + 33554432ull);
  _Float16* WThi = (_Float16*)(ws + 67108864ull);      // 16,777,216 B
  _Float16* WTlo = (_Float16*)(ws + 83886080ull);
  float* partial = (float*)(ws + 100663296ull);        // 64*8192*4 = 2 MB
  int* idx1 = (int*)(ws + 102760448ull);
  int* idx2 = idx1 + Mm;
  float* p1 = (float*)(idx2 + Mm);
  float* p2 = p1 + Mm;
  int* prios = (int*)(p2 + Mm);

  split_x<<<(Mm * Dd) / 1024, 256, 0, stream>>>(X, Xhi, Xlo);
  transpose_w<<<dim3(32, 8, 8), 256, 0, stream>>>(W, WThi, WTlo);
  gemm_mfma<<<dim3(64, 32), 256, 0, stream>>>(Xhi, Xlo, WThi, WTlo, partial);
  route_kernel<<<Mm / 256, 256, 0, stream>>>(partial, idx1, idx2, p1, p2);
  scan_kernel<<<Bb, 256, 0, stream>>>(idx1, idx2, prios);
  const int n4 = out_size / 4;
  zero_kernel<<<(n4 + 255) / 256, 256, 0, stream>>>((float4*)out, n4);
  scatter_kernel<<<Mm / 256, 256, 0, stream>>>(idx1, idx2, p1, p2, prios, out, cap);
}